// Round 1
// baseline (1122.490 us; speedup 1.0000x reference)
//
#include <hip/hip_runtime.h>
#include <cstdint>
#include <cstddef>

static constexpr int NN    = 100000;
static constexpr int NE    = 1600000;
static constexpr int IN_C  = 128;
static constexpr int HID_C = 64;
static constexpr int OUT_C = 32;

static inline int cdiv(int a, int b) { return (a + b - 1) / b; }

__global__ void deg_kernel(const int* __restrict__ row, float* __restrict__ deg, int E) {
    int i = blockIdx.x * 256 + threadIdx.x;
    if (i < E) atomicAdd(&deg[row[i]], 1.0f);
}

__global__ void dis_kernel(const float* __restrict__ deg, float* __restrict__ dis, int n) {
    int i = blockIdx.x * 256 + threadIdx.x;
    if (i < n) {
        float d = deg[i];
        dis[i] = d > 0.0f ? rsqrtf(fmaxf(d, 1.0f)) : 0.0f;
    }
}

// Block-exclusive scan of (int)deg into row_start; per-block totals into partials.
__global__ void scan1_kernel(const float* __restrict__ deg, int* __restrict__ row_start,
                             int* __restrict__ partials, int n) {
    __shared__ int tmp[256];
    int t = threadIdx.x;
    int i = blockIdx.x * 256 + t;
    int v = (i < n) ? (int)deg[i] : 0;
    tmp[t] = v;
    __syncthreads();
    for (int off = 1; off < 256; off <<= 1) {
        int add = (t >= off) ? tmp[t - off] : 0;
        __syncthreads();
        tmp[t] += add;
        __syncthreads();
    }
    if (i < n) row_start[i] = tmp[t] - v;
    if (t == 255) partials[blockIdx.x] = tmp[t];
}

__global__ void scan2_kernel(int* __restrict__ partials, int nparts) {
    __shared__ int tmp[512];
    int t = threadIdx.x;
    int v = (t < nparts) ? partials[t] : 0;
    tmp[t] = v;
    __syncthreads();
    for (int off = 1; off < 512; off <<= 1) {
        int add = (t >= off) ? tmp[t - off] : 0;
        __syncthreads();
        tmp[t] += add;
        __syncthreads();
    }
    if (t < nparts) partials[t] = tmp[t] - v;
}

__global__ void scan3_kernel(int* __restrict__ row_start, const int* __restrict__ partials,
                             int* __restrict__ cursor, int n, int total) {
    int i = blockIdx.x * 256 + threadIdx.x;
    if (i < n) {
        int v = row_start[i] + partials[blockIdx.x];
        row_start[i] = v;
        cursor[i] = v;
    }
    if (i == 0) row_start[n] = total;
}

__global__ void scatter_kernel(const int* __restrict__ row, const int* __restrict__ col,
                               const float* __restrict__ dis, int* __restrict__ cursor,
                               int* __restrict__ csr_col, float* __restrict__ csr_w, int E) {
    int i = blockIdx.x * 256 + threadIdx.x;
    if (i < E) {
        int r = row[i], c = col[i];
        int pos = atomicAdd(&cursor[r], 1);
        csr_col[pos] = c;
        csr_w[pos]   = -dis[r] * dis[c];
    }
}

// A layout: A[c][kk*Cout + o], where A0=W0-W2, A1=W1-3W3, A2=2W2, A3=4W3.
__global__ void wtrans_kernel(const float* __restrict__ W, float* __restrict__ A,
                              int Cin, int Cout) {
    int idx = blockIdx.x * 256 + threadIdx.x;
    int total = Cin * 4 * Cout;
    if (idx >= total) return;
    int o  = idx % Cout;
    int kk = (idx / Cout) & 3;
    int c  = idx / (4 * Cout);
    size_t s = (size_t)Cin * Cout;
    float v;
    if (kk == 0)      v = W[0 * s + (size_t)c * Cout + o] - W[2 * s + (size_t)c * Cout + o];
    else if (kk == 1) v = W[1 * s + (size_t)c * Cout + o] - 3.0f * W[3 * s + (size_t)c * Cout + o];
    else if (kk == 2) v = 2.0f * W[2 * s + (size_t)c * Cout + o];
    else              v = 4.0f * W[3 * s + (size_t)c * Cout + o];
    A[idx] = v;   // idx == c*(4*Cout) + kk*Cout + o
}

// Y[n..][M] = X[n..][Kdim] @ A[Kdim][M]. 64x64 output tile / block, 256 threads,
// each thread 4x4. k-major LDS tiles: xs[k][r], ws[k][c] (pad 68 keeps float4 align).
__global__ __launch_bounds__(256) void matmul64_kernel(
        const float* __restrict__ X, const float* __restrict__ A,
        float* __restrict__ Y, int n, int Kdim, int M) {
    __shared__ float xs[64][68];
    __shared__ float ws[64][68];
    int row0 = blockIdx.x * 64, col0 = blockIdx.y * 64;
    int tid = threadIdx.x;
    int tr = tid >> 4;    // 0..15 row group
    int tc = tid & 15;    // 0..15 col group (fastest -> coalesced stores)
    float acc[4][4] = {};
    for (int kt = 0; kt < Kdim; kt += 64) {
#pragma unroll
        for (int l = 0; l < 4; ++l) {
            int idx = (tid + l * 256) * 4;   // element index in 64x64 tile
            int r = idx >> 6, c = idx & 63;
            float4 v = make_float4(0.f, 0.f, 0.f, 0.f);
            int gr = row0 + r;
            if (gr < n) v = *(const float4*)(X + (size_t)gr * Kdim + kt + c);
            xs[c + 0][r] = v.x; xs[c + 1][r] = v.y; xs[c + 2][r] = v.z; xs[c + 3][r] = v.w;
            int k = r;                        // same decomposition for the A tile
            float4 w4 = *(const float4*)(A + (size_t)(kt + k) * M + col0 + c);
            *(float4*)&ws[k][c] = w4;
        }
        __syncthreads();
#pragma unroll
        for (int k = 0; k < 64; ++k) {
            float4 xa = *(const float4*)&xs[k][tr * 4];
            float4 wb = *(const float4*)&ws[k][tc * 4];
            float xv[4] = {xa.x, xa.y, xa.z, xa.w};
            float wv[4] = {wb.x, wb.y, wb.z, wb.w};
#pragma unroll
            for (int i = 0; i < 4; ++i)
#pragma unroll
                for (int j = 0; j < 4; ++j)
                    acc[i][j] = fmaf(xv[i], wv[j], acc[i][j]);
        }
        __syncthreads();
    }
#pragma unroll
    for (int i = 0; i < 4; ++i) {
        int gr = row0 + tr * 4 + i;
        if (gr < n) {
            float4 v = make_float4(acc[i][0], acc[i][1], acc[i][2], acc[i][3]);
            *(float4*)(Y + (size_t)gr * M + col0 + tc * 4) = v;
        }
    }
}

// out[node,:] = Zadd[node,:] + sum_e w_e * Ssrc[col_e,:]  (+bias, relu, log_softmax)
// One C-lane group per node; lane == channel.
template <int C, bool RELU, bool BIAS, bool LSM>
__global__ __launch_bounds__(256) void prop_kernel(
        const int* __restrict__ row_start,
        const int* __restrict__ csr_col, const float* __restrict__ csr_w,
        const float* __restrict__ Ssrc, int ld_src,
        const float* __restrict__ Zadd, int ld_add,
        const float* __restrict__ bias,
        float* __restrict__ out, int ld_out, int n) {
    constexpr int NPB = 256 / C;
    int g    = threadIdx.x / C;
    int lane = threadIdx.x % C;
    int node = blockIdx.x * NPB + g;
    if (node >= n) return;
    int s = row_start[node], e = row_start[node + 1];
    float acc = 0.0f;
    for (int i = s; i < e; ++i) {
        int   c = csr_col[i];
        float w = csr_w[i];
        acc = fmaf(w, Ssrc[(size_t)c * ld_src + lane], acc);
    }
    float v = Zadd[(size_t)node * ld_add + lane] + acc;
    if (BIAS) v += bias[lane];
    if (RELU) v = fmaxf(v, 0.0f);
    if (LSM) {
        float m = v;
#pragma unroll
        for (int off = 16; off > 0; off >>= 1) m = fmaxf(m, __shfl_xor(m, off, 32));
        float ex = __expf(v - m);
        float sum = ex;
#pragma unroll
        for (int off = 16; off > 0; off >>= 1) sum += __shfl_xor(sum, off, 32);
        v = (v - m) - __logf(sum);
    }
    out[(size_t)node * ld_out + lane] = v;
}

extern "C" void kernel_launch(void* const* d_in, const int* in_sizes, int n_in,
                              void* d_out, int out_size, void* d_ws, size_t ws_size,
                              hipStream_t stream) {
    const float* x  = (const float*)d_in[0];
    const int*   ei = (const int*)d_in[1];
    const float* W1 = (const float*)d_in[2];
    const float* b1 = (const float*)d_in[3];
    const float* W2 = (const float*)d_in[4];
    const float* b2 = (const float*)d_in[5];
    float* out = (float*)d_out;

    const int* row = ei;
    const int* col = ei + NE;

    char* p = (char*)d_ws;
    auto alloc = [&](size_t bytes) {
        char* q = p;
        p += (bytes + 255) & ~(size_t)255;
        return q;
    };
    float* deg       = (float*)alloc((size_t)NN * 4);
    float* dis       = (float*)alloc((size_t)NN * 4);
    int*   row_start = (int*)alloc((size_t)(NN + 1) * 4);
    int*   cursor    = (int*)alloc((size_t)NN * 4);
    int*   partials  = (int*)alloc(512 * 4);
    int*   csr_col   = (int*)alloc((size_t)NE * 4);
    float* csr_w     = (float*)alloc((size_t)NE * 4);
    float* A1        = (float*)alloc((size_t)IN_C * 4 * HID_C * 4);
    float* A2        = (float*)alloc((size_t)HID_C * 4 * OUT_C * 4);
    float* ZZ        = (float*)alloc((size_t)NN * 256 * 4);  // layer1 Z; reused as layer2 Z
    float* Sa        = (float*)alloc((size_t)NN * 64 * 4);
    float* Sb        = (float*)alloc((size_t)NN * 64 * 4);
    float* h         = (float*)alloc((size_t)NN * 64 * 4);

    hipMemsetAsync(deg, 0, (size_t)NN * 4, stream);
    deg_kernel<<<cdiv(NE, 256), 256, 0, stream>>>(row, deg, NE);
    dis_kernel<<<cdiv(NN, 256), 256, 0, stream>>>(deg, dis, NN);
    scan1_kernel<<<cdiv(NN, 256), 256, 0, stream>>>(deg, row_start, partials, NN);
    scan2_kernel<<<1, 512, 0, stream>>>(partials, cdiv(NN, 256));
    scan3_kernel<<<cdiv(NN, 256), 256, 0, stream>>>(row_start, partials, cursor, NN, NE);
    scatter_kernel<<<cdiv(NE, 256), 256, 0, stream>>>(row, col, dis, cursor, csr_col, csr_w, NE);

    wtrans_kernel<<<cdiv(IN_C * 4 * HID_C, 256), 256, 0, stream>>>(W1, A1, IN_C, HID_C);
    wtrans_kernel<<<cdiv(HID_C * 4 * OUT_C, 256), 256, 0, stream>>>(W2, A2, HID_C, OUT_C);

    // Layer 1: ZZ[N,256] = x @ A1, then Horner props at C=64.
    {
        dim3 g1(cdiv(NN, 64), 4);
        matmul64_kernel<<<g1, 256, 0, stream>>>(x, A1, ZZ, NN, IN_C, 256);
    }
    prop_kernel<64, false, false, false><<<cdiv(NN, 4), 256, 0, stream>>>(
        row_start, csr_col, csr_w, ZZ + 3 * 64, 256, ZZ + 2 * 64, 256, nullptr, Sa, 64, NN);
    prop_kernel<64, false, false, false><<<cdiv(NN, 4), 256, 0, stream>>>(
        row_start, csr_col, csr_w, Sa, 64, ZZ + 1 * 64, 256, nullptr, Sb, 64, NN);
    prop_kernel<64, true, true, false><<<cdiv(NN, 4), 256, 0, stream>>>(
        row_start, csr_col, csr_w, Sb, 64, ZZ + 0, 256, b1, h, 64, NN);

    // Layer 2: ZZ[N,128] = h @ A2 (reuse ZZ), Horner props at C=32, fused log_softmax.
    {
        dim3 g2(cdiv(NN, 64), 2);
        matmul64_kernel<<<g2, 256, 0, stream>>>(h, A2, ZZ, NN, HID_C, 128);
    }
    prop_kernel<32, false, false, false><<<cdiv(NN, 8), 256, 0, stream>>>(
        row_start, csr_col, csr_w, ZZ + 3 * 32, 128, ZZ + 2 * 32, 128, nullptr, Sa, 32, NN);
    prop_kernel<32, false, false, false><<<cdiv(NN, 8), 256, 0, stream>>>(
        row_start, csr_col, csr_w, Sa, 32, ZZ + 1 * 32, 128, nullptr, Sb, 32, NN);
    prop_kernel<32, false, true, true><<<cdiv(NN, 8), 256, 0, stream>>>(
        row_start, csr_col, csr_w, Sb, 32, ZZ + 0, 128, b2, out, 32, NN);
}

// Round 3
// 725.167 us; speedup vs baseline: 1.5479x; 1.5479x over previous
//
#include <hip/hip_runtime.h>
#include <hip/hip_fp16.h>
#include <cstdint>
#include <cstddef>

static constexpr int NN    = 100000;
static constexpr int NE    = 1600000;
static constexpr int IN_C  = 128;
static constexpr int HID_C = 64;
static constexpr int OUT_C = 32;

static inline int cdiv(int a, int b) { return (a + b - 1) / b; }

__global__ void deg_kernel(const int* __restrict__ row, float* __restrict__ deg, int E) {
    int i = blockIdx.x * 256 + threadIdx.x;
    if (i < E) atomicAdd(&deg[row[i]], 1.0f);
}

__global__ void dis_kernel(const float* __restrict__ deg, float* __restrict__ dis, int n) {
    int i = blockIdx.x * 256 + threadIdx.x;
    if (i < n) {
        float d = deg[i];
        dis[i] = d > 0.0f ? rsqrtf(fmaxf(d, 1.0f)) : 0.0f;
    }
}

// Block-exclusive scan of (int)deg into row_start; per-block totals into partials.
__global__ void scan1_kernel(const float* __restrict__ deg, int* __restrict__ row_start,
                             int* __restrict__ partials, int n) {
    __shared__ int tmp[256];
    int t = threadIdx.x;
    int i = blockIdx.x * 256 + t;
    int v = (i < n) ? (int)deg[i] : 0;
    tmp[t] = v;
    __syncthreads();
    for (int off = 1; off < 256; off <<= 1) {
        int add = (t >= off) ? tmp[t - off] : 0;
        __syncthreads();
        tmp[t] += add;
        __syncthreads();
    }
    if (i < n) row_start[i] = tmp[t] - v;
    if (t == 255) partials[blockIdx.x] = tmp[t];
}

__global__ void scan2_kernel(int* __restrict__ partials, int nparts) {
    __shared__ int tmp[512];
    int t = threadIdx.x;
    int v = (t < nparts) ? partials[t] : 0;
    tmp[t] = v;
    __syncthreads();
    for (int off = 1; off < 512; off <<= 1) {
        int add = (t >= off) ? tmp[t - off] : 0;
        __syncthreads();
        tmp[t] += add;
        __syncthreads();
    }
    if (t < nparts) partials[t] = tmp[t] - v;
}

__global__ void scan3_kernel(int* __restrict__ row_start, const int* __restrict__ partials,
                             int* __restrict__ cursor, int n, int total) {
    int i = blockIdx.x * 256 + threadIdx.x;
    if (i < n) {
        int v = row_start[i] + partials[blockIdx.x];
        row_start[i] = v;
        cursor[i] = v;
    }
    if (i == 0) row_start[n] = total;
}

__global__ void scatter_kernel(const int* __restrict__ row, const int* __restrict__ col,
                               int* __restrict__ cursor, int* __restrict__ csr_col, int E) {
    int i = blockIdx.x * 256 + threadIdx.x;
    if (i < E) {
        int r = row[i];
        int pos = atomicAdd(&cursor[r], 1);
        csr_col[pos] = col[i];
    }
}

// A layout: A[c][kk*Cout + o], where A0=W0-W2, A1=W1-3W3, A2=2W2, A3=4W3.
__global__ void wtrans_kernel(const float* __restrict__ W, float* __restrict__ A,
                              int Cin, int Cout) {
    int idx = blockIdx.x * 256 + threadIdx.x;
    int total = Cin * 4 * Cout;
    if (idx >= total) return;
    int o  = idx % Cout;
    int kk = (idx / Cout) & 3;
    int c  = idx / (4 * Cout);
    size_t s = (size_t)Cin * Cout;
    float v;
    if (kk == 0)      v = W[0 * s + (size_t)c * Cout + o] - W[2 * s + (size_t)c * Cout + o];
    else if (kk == 1) v = W[1 * s + (size_t)c * Cout + o] - 3.0f * W[3 * s + (size_t)c * Cout + o];
    else if (kk == 2) v = 2.0f * W[2 * s + (size_t)c * Cout + o];
    else              v = 4.0f * W[3 * s + (size_t)c * Cout + o];
    A[idx] = v;   // idx == c*(4*Cout) + kk*Cout + o
}

// Y[n..][M] = X[n..][Kdim] @ A[Kdim][M], output __half.
// Columns >= c3b (the Z3 slice) are pre-scaled by dis[row] so the following
// propagation gathers need no per-edge weight.
// 64x64 tile / block, 256 threads, 4x4 per thread, k-major LDS tiles.
template <typename TI>
__global__ __launch_bounds__(256) void matmul64_kernel(
        const TI* __restrict__ X, const float* __restrict__ A,
        __half* __restrict__ Y, const float* __restrict__ dis,
        int n, int Kdim, int M, int c3b) {
    __shared__ float xs[64][68];
    __shared__ float ws[64][68];
    int row0 = blockIdx.x * 64, col0 = blockIdx.y * 64;
    int tid = threadIdx.x;
    int tr = tid >> 4;    // 0..15 row group
    int tc = tid & 15;    // 0..15 col group
    float acc[4][4] = {};
    for (int kt = 0; kt < Kdim; kt += 64) {
#pragma unroll
        for (int l = 0; l < 4; ++l) {
            int idx = (tid + l * 256) * 4;   // element index in 64x64 tile
            int r = idx >> 6, c = idx & 63;
            float4 v = make_float4(0.f, 0.f, 0.f, 0.f);
            int gr = row0 + r;
            if (gr < n) {
                if constexpr (sizeof(TI) == 4) {
                    v = *(const float4*)((const float*)X + (size_t)gr * Kdim + kt + c);
                } else {
                    const __half2* q = (const __half2*)((const __half*)X + (size_t)gr * Kdim + kt + c);
                    float2 f0 = __half22float2(q[0]);
                    float2 f1 = __half22float2(q[1]);
                    v = make_float4(f0.x, f0.y, f1.x, f1.y);
                }
            }
            xs[c + 0][r] = v.x; xs[c + 1][r] = v.y; xs[c + 2][r] = v.z; xs[c + 3][r] = v.w;
            int k = r;
            float4 w4 = *(const float4*)(A + (size_t)(kt + k) * M + col0 + c);
            *(float4*)&ws[k][c] = w4;
        }
        __syncthreads();
#pragma unroll
        for (int k = 0; k < 64; ++k) {
            float4 xa = *(const float4*)&xs[k][tr * 4];
            float4 wb = *(const float4*)&ws[k][tc * 4];
            float xv[4] = {xa.x, xa.y, xa.z, xa.w};
            float wv[4] = {wb.x, wb.y, wb.z, wb.w};
#pragma unroll
            for (int i = 0; i < 4; ++i)
#pragma unroll
                for (int j = 0; j < 4; ++j)
                    acc[i][j] = fmaf(xv[i], wv[j], acc[i][j]);
        }
        __syncthreads();
    }
    bool z3 = (col0 + tc * 4) >= c3b;   // c3b is 4-aligned; all 4 cols share it
#pragma unroll
    for (int i = 0; i < 4; ++i) {
        int gr = row0 + tr * 4 + i;
        if (gr < n) {
            float s = z3 ? dis[gr] : 1.0f;
            union { uint2 u; __half2 h[2]; } pk;
            pk.h[0] = __floats2half2_rn(acc[i][0] * s, acc[i][1] * s);
            pk.h[1] = __floats2half2_rn(acc[i][2] * s, acc[i][3] * s);
            *(uint2*)(Y + (size_t)gr * M + col0 + tc * 4) = pk.u;
        }
    }
}

// out[node,:] = Zadd[node,:] - dis[node] * sum_e Ssrc[col_e,:]  (+bias, relu, lsm)
// Ssrc rows are pre-scaled by dis at their producer, so no per-edge weight.
// If PRESCALE, the stored value is dis[node]*v (feeding the next propagation).
template <int C, bool RELU, bool BIAS, bool LSM, bool PRESCALE, typename TO>
__global__ __launch_bounds__(256) void prop_kernel(
        const int* __restrict__ row_start,
        const int* __restrict__ csr_col,
        const float* __restrict__ dis,
        const __half* __restrict__ Ssrc, int ld_src,
        const __half* __restrict__ Zadd, int ld_add,
        const float* __restrict__ bias,
        TO* __restrict__ out, int ld_out, int n) {
    constexpr int NPB = 256 / C;
    int g    = threadIdx.x / C;
    int lane = threadIdx.x % C;
    int node = blockIdx.x * NPB + g;
    if (node >= n) return;
    int s = row_start[node], e = row_start[node + 1];
    if (C == 64) {   // wave-uniform bounds -> scalar loads for col indices
        s = __builtin_amdgcn_readfirstlane(s);
        e = __builtin_amdgcn_readfirstlane(e);
    }
    float dn = dis[node];
    float acc = 0.0f;
    int i = s;
    for (; i + 4 <= e; i += 4) {
        int c0 = csr_col[i], c1 = csr_col[i + 1], c2 = csr_col[i + 2], c3 = csr_col[i + 3];
        float v0 = __half2float(Ssrc[(size_t)c0 * ld_src + lane]);
        float v1 = __half2float(Ssrc[(size_t)c1 * ld_src + lane]);
        float v2 = __half2float(Ssrc[(size_t)c2 * ld_src + lane]);
        float v3 = __half2float(Ssrc[(size_t)c3 * ld_src + lane]);
        acc += (v0 + v1) + (v2 + v3);
    }
    for (; i < e; ++i)
        acc += __half2float(Ssrc[(size_t)csr_col[i] * ld_src + lane]);

    float v = fmaf(-dn, acc, __half2float(Zadd[(size_t)node * ld_add + lane]));
    if (BIAS) v += bias[lane];
    if (RELU) v = fmaxf(v, 0.0f);
    if (LSM) {
        float m = v;
#pragma unroll
        for (int off = 16; off > 0; off >>= 1) m = fmaxf(m, __shfl_xor(m, off, 32));
        float ex = __expf(v - m);
        float sum = ex;
#pragma unroll
        for (int off = 16; off > 0; off >>= 1) sum += __shfl_xor(sum, off, 32);
        v = (v - m) - __logf(sum);
    }
    if (PRESCALE) v *= dn;
    if constexpr (sizeof(TO) == 2) {
        out[(size_t)node * ld_out + lane] = (TO)__float2half_rn(v);
    } else {
        out[(size_t)node * ld_out + lane] = v;
    }
}

extern "C" void kernel_launch(void* const* d_in, const int* in_sizes, int n_in,
                              void* d_out, int out_size, void* d_ws, size_t ws_size,
                              hipStream_t stream) {
    const float* x  = (const float*)d_in[0];
    const int*   ei = (const int*)d_in[1];
    const float* W1 = (const float*)d_in[2];
    const float* b1 = (const float*)d_in[3];
    const float* W2 = (const float*)d_in[4];
    const float* b2 = (const float*)d_in[5];
    float* out = (float*)d_out;

    const int* row = ei;
    const int* col = ei + NE;

    char* p = (char*)d_ws;
    auto alloc = [&](size_t bytes) {
        char* q = p;
        p += (bytes + 255) & ~(size_t)255;
        return q;
    };
    float*  deg       = (float*)alloc((size_t)NN * 4);
    float*  dis       = (float*)alloc((size_t)NN * 4);
    int*    row_start = (int*)alloc((size_t)(NN + 1) * 4);
    int*    cursor    = (int*)alloc((size_t)NN * 4);
    int*    partials  = (int*)alloc(512 * 4);
    int*    csr_col   = (int*)alloc((size_t)NE * 4);
    float*  A1        = (float*)alloc((size_t)IN_C * 4 * HID_C * 4);
    float*  A2        = (float*)alloc((size_t)HID_C * 4 * OUT_C * 4);
    __half* ZZ        = (__half*)alloc((size_t)NN * 256 * 2);  // layer1 Z; reused layer2
    __half* Sa        = (__half*)alloc((size_t)NN * 64 * 2);
    __half* Sb        = (__half*)alloc((size_t)NN * 64 * 2);
    __half* h         = (__half*)alloc((size_t)NN * 64 * 2);

    hipMemsetAsync(deg, 0, (size_t)NN * 4, stream);
    deg_kernel<<<cdiv(NE, 256), 256, 0, stream>>>(row, deg, NE);
    dis_kernel<<<cdiv(NN, 256), 256, 0, stream>>>(deg, dis, NN);
    scan1_kernel<<<cdiv(NN, 256), 256, 0, stream>>>(deg, row_start, partials, NN);
    scan2_kernel<<<1, 512, 0, stream>>>(partials, cdiv(NN, 256));
    scan3_kernel<<<cdiv(NN, 256), 256, 0, stream>>>(row_start, partials, cursor, NN, NE);
    scatter_kernel<<<cdiv(NE, 256), 256, 0, stream>>>(row, col, cursor, csr_col, NE);

    wtrans_kernel<<<cdiv(IN_C * 4 * HID_C, 256), 256, 0, stream>>>(W1, A1, IN_C, HID_C);
    wtrans_kernel<<<cdiv(HID_C * 4 * OUT_C, 256), 256, 0, stream>>>(W2, A2, HID_C, OUT_C);

    // Layer 1: ZZ[N,256] = x @ A1 (Z3 slice pre-scaled by dis), Horner props C=64.
    {
        dim3 g1(cdiv(NN, 64), 4);
        matmul64_kernel<float><<<g1, 256, 0, stream>>>(x, A1, ZZ, dis, NN, IN_C, 256, 3 * HID_C);
    }
    prop_kernel<64, false, false, false, true,  __half><<<cdiv(NN, 4), 256, 0, stream>>>(
        row_start, csr_col, dis, ZZ + 3 * 64, 256, ZZ + 2 * 64, 256, nullptr, Sa, 64, NN);
    prop_kernel<64, false, false, false, true,  __half><<<cdiv(NN, 4), 256, 0, stream>>>(
        row_start, csr_col, dis, Sa, 64, ZZ + 1 * 64, 256, nullptr, Sb, 64, NN);
    prop_kernel<64, true,  true,  false, false, __half><<<cdiv(NN, 4), 256, 0, stream>>>(
        row_start, csr_col, dis, Sb, 64, ZZ + 0, 256, b1, h, 64, NN);

    // Layer 2: ZZ[N,128] = h @ A2, Horner props C=32, fused log_softmax.
    {
        dim3 g2(cdiv(NN, 64), 2);
        matmul64_kernel<__half><<<g2, 256, 0, stream>>>(h, A2, ZZ, dis, NN, HID_C, 128, 3 * OUT_C);
    }
    prop_kernel<32, false, false, false, true,  __half><<<cdiv(NN, 8), 256, 0, stream>>>(
        row_start, csr_col, dis, ZZ + 3 * 32, 128, ZZ + 2 * 32, 128, nullptr, Sa, 32, NN);
    prop_kernel<32, false, false, false, true,  __half><<<cdiv(NN, 8), 256, 0, stream>>>(
        row_start, csr_col, dis, Sa, 32, ZZ + 1 * 32, 128, nullptr, Sb, 32, NN);
    prop_kernel<32, false, true,  true,  false, float><<<cdiv(NN, 8), 256, 0, stream>>>(
        row_start, csr_col, dis, Sb, 32, ZZ + 0, 128, b2, out, 32, NN);
}